// Round 1
// baseline (33.830 us; speedup 1.0000x reference)
//
#include <hip/hip_runtime.h>
#include <hip/hip_bf16.h>
#include <stdint.h>

// ---------------------------------------------------------------------------
// Kernel A: per batch row, compact the boolean mask into an index list.
// grid = B blocks, block = 64 threads (one wave).
// Emits idx[b*max_len + j] = s for the j-th kept position, and counts[b].
// Handles mask stored as 4-byte words (int32 0/1 or f32 0.0/1.0) OR as raw
// bytes, auto-detected from the first 64 words (256B, in-bounds either way).
// ---------------------------------------------------------------------------
__global__ void __launch_bounds__(64)
compact_index_kernel(const uint32_t* __restrict__ mask_words,
                     int S, int max_len,
                     int* __restrict__ idx, int* __restrict__ counts) {
    const int b    = blockIdx.x;
    const int lane = threadIdx.x;   // 0..63

    // --- detect layout: sample 64 words = 256 bytes (safe under byte layout:
    // total byte buffer is B*S >= 256 bytes). Word layout => every word is
    // 0, 1, or 0x3F800000 (1.0f). Byte layout (random 0/1 bytes packed 4/word)
    // => essentially surely some other value appears.
    uint32_t w0 = mask_words[lane];
    bool weird = (w0 > 1u) && (w0 != 0x3F800000u);
    bool bytemode = (__ballot(weird) != 0ULL);

    const uint8_t* mask_bytes = (const uint8_t*)mask_words;
    const size_t row_base = (size_t)b * (size_t)S;

    int total = 0;
    const int nchunk = S / 64;            // S=4096 -> 64 chunks
    for (int cg = 0; cg < nchunk; cg += 8) {
        uint32_t v[8];
        if (bytemode) {
            #pragma unroll
            for (int k = 0; k < 8; ++k)
                v[k] = (uint32_t)mask_bytes[row_base + (size_t)(cg + k) * 64 + lane];
        } else {
            #pragma unroll
            for (int k = 0; k < 8; ++k)
                v[k] = mask_words[row_base + (size_t)(cg + k) * 64 + lane];
        }
        #pragma unroll
        for (int k = 0; k < 8; ++k) {
            unsigned long long bm = __ballot(v[k] != 0u);
            if (v[k] != 0u) {
                int j = total + (int)__popcll(bm & ((1ULL << lane) - 1ULL));
                idx[b * max_len + j] = (cg + k) * 64 + lane;
            }
            total += (int)__popcll(bm);
        }
    }
    if (lane == 0) counts[b] = total;
}

// ---------------------------------------------------------------------------
// Kernel B: gather + zero-pad. Each block (256 threads) handles ROWS_PER_BLOCK
// consecutive output rows of one batch; each thread moves one float4 per row
// (D=1024 floats = 256 float4). Fully coalesced reads and writes.
// ---------------------------------------------------------------------------
#define ROWS_PER_BLOCK 4

__global__ void __launch_bounds__(256)
gather_pad_kernel(const float* __restrict__ hs,
                  const int* __restrict__ idx,
                  const int* __restrict__ counts,
                  float* __restrict__ out,
                  int S, int D, int max_len) {
    const int b  = blockIdx.y;
    const int t  = threadIdx.x;          // 0..255, D/4 float4 slots
    const int j0 = blockIdx.x * ROWS_PER_BLOCK;
    const int cnt = counts[b];

    #pragma unroll
    for (int r = 0; r < ROWS_PER_BLOCK; ++r) {
        const int j = j0 + r;
        if (j >= max_len) break;
        float4 val = make_float4(0.f, 0.f, 0.f, 0.f);
        if (j < cnt) {
            const int s = idx[b * max_len + j];
            const float4* src =
                (const float4*)(hs + ((size_t)b * S + (size_t)s) * (size_t)D);
            val = src[t];
        }
        float4* dst = (float4*)(out + ((size_t)b * max_len + (size_t)j) * (size_t)D);
        dst[t] = val;
    }
}

extern "C" void kernel_launch(void* const* d_in, const int* in_sizes, int n_in,
                              void* d_out, int out_size, void* d_ws, size_t ws_size,
                              hipStream_t stream) {
    const float*    hs   = (const float*)d_in[0];
    const uint32_t* mask = (const uint32_t*)d_in[1];

    const int B  = 8;                       // per reference setup
    const int BS = in_sizes[1];             // B * S
    const int S  = BS / B;                  // 4096
    const int D  = in_sizes[0] / BS;        // 1024
    const int max_len = out_size / (B * D); // data-dependent but fixed per run

    // workspace layout: counts[B] (first 256B for alignment), then idx[B*max_len]
    int* counts = (int*)d_ws;
    int* idx    = (int*)((char*)d_ws + 256);

    compact_index_kernel<<<B, 64, 0, stream>>>(mask, S, max_len, idx, counts);

    dim3 grid((max_len + ROWS_PER_BLOCK - 1) / ROWS_PER_BLOCK, B);
    gather_pad_kernel<<<grid, 256, 0, stream>>>(
        (const float*)hs, idx, counts, (float*)d_out, S, D, max_len);
}

// Round 2
// 29.695 us; speedup vs baseline: 1.1392x; 1.1392x over previous
//
#include <hip/hip_runtime.h>
#include <hip/hip_bf16.h>
#include <stdint.h>

// ---------------------------------------------------------------------------
// Kernel A: per batch row, compact the boolean mask into an index list.
// grid = B blocks, block = 1024 threads (16 waves). Each wave handles
// nchunk/16 chunks of 64 positions: ballot-based rank within the wave's
// span, LDS exclusive scan of wave totals, then ordered idx writes.
// Mask stored as 4-byte words (int32 0/1 or f32 0.0/1.0) OR raw bytes,
// auto-detected from the first 64 words (256B, in-bounds either way).
// ---------------------------------------------------------------------------
#define WAVES_A 16

__global__ void __launch_bounds__(64 * WAVES_A)
compact_index_kernel(const uint32_t* __restrict__ mask_words,
                     int S, int stride,
                     int* __restrict__ idx, int* __restrict__ counts) {
    const int b    = blockIdx.x;
    const int t    = threadIdx.x;
    const int wave = t >> 6;
    const int lane = t & 63;

    // layout detection: every wave samples the same first 64 words (cached).
    uint32_t w0 = mask_words[lane];
    bool weird = (w0 > 1u) && (w0 != 0x3F800000u);
    bool bytemode = (__ballot(weird) != 0ULL);

    const uint8_t* mask_bytes = (const uint8_t*)mask_words;
    const size_t row_base = (size_t)b * (size_t)S;

    const int nchunk = S / 64;          // 64 for S=4096
    const int cpw    = nchunk / WAVES_A; // 4 chunks per wave
    const int c0     = wave * cpw;

    uint32_t v[8];                       // cpw <= 8
    if (bytemode) {
        #pragma unroll
        for (int k = 0; k < 4; ++k)
            if (k < cpw)
                v[k] = (uint32_t)mask_bytes[row_base + (size_t)(c0 + k) * 64 + lane];
    } else {
        #pragma unroll
        for (int k = 0; k < 4; ++k)
            if (k < cpw)
                v[k] = mask_words[row_base + (size_t)(c0 + k) * 64 + lane];
    }

    unsigned long long bm[4];
    int wave_total = 0;
    #pragma unroll
    for (int k = 0; k < 4; ++k) {
        if (k < cpw) {
            bm[k] = __ballot(v[k] != 0u);
            wave_total += (int)__popcll(bm[k]);
        }
    }

    __shared__ int wtot[WAVES_A];
    if (lane == 0) wtot[wave] = wave_total;
    __syncthreads();

    int base = 0;
    for (int w = 0; w < wave; ++w) base += wtot[w];

    #pragma unroll
    for (int k = 0; k < 4; ++k) {
        if (k < cpw) {
            if (v[k] != 0u) {
                int j = base + (int)__popcll(bm[k] & ((1ULL << lane) - 1ULL));
                idx[(size_t)b * stride + j] = (c0 + k) * 64 + lane;
            }
            base += (int)__popcll(bm[k]);
        }
    }

    if (t == 0) {
        int tot = 0;
        #pragma unroll
        for (int w = 0; w < WAVES_A; ++w) tot += wtot[w];
        counts[b] = tot;
    }
}

// ---------------------------------------------------------------------------
// Kernel B: gather + zero-pad. Each block (256 threads) handles 4 consecutive
// output rows of one batch; each thread moves one float4 per row (D=1024
// floats = 256 float4). The 4 source indices load as one aligned int4; all
// 4 row loads are issued before any store for memory-level parallelism.
// ---------------------------------------------------------------------------
__global__ void __launch_bounds__(256)
gather_pad_kernel(const float* __restrict__ hs,
                  const int* __restrict__ idx,
                  const int* __restrict__ counts,
                  float* __restrict__ out,
                  int S, int D, int max_len, int stride) {
    const int b   = blockIdx.y;
    const int t   = threadIdx.x;          // 0..255 -> float4 slot
    const int j0  = blockIdx.x * 4;
    const int cnt = counts[b];

    // stride % 4 == 0 and j0 % 4 == 0 -> 16B-aligned; padding rows within
    // the allocated stride, so the vector load is always in-bounds.
    int4 sidx = *(const int4*)(idx + (size_t)b * stride + j0);
    const int sj[4] = {sidx.x, sidx.y, sidx.z, sidx.w};

    float4 val[4];
    #pragma unroll
    for (int r = 0; r < 4; ++r) {
        val[r] = make_float4(0.f, 0.f, 0.f, 0.f);
        const int j = j0 + r;
        if (j < cnt) {
            const float4* src =
                (const float4*)(hs + ((size_t)b * S + (size_t)sj[r]) * (size_t)D);
            val[r] = src[t];
        }
    }

    #pragma unroll
    for (int r = 0; r < 4; ++r) {
        const int j = j0 + r;
        if (j < max_len) {
            float4* dst =
                (float4*)(out + ((size_t)b * max_len + (size_t)j) * (size_t)D);
            dst[t] = val[r];
        }
    }
}

extern "C" void kernel_launch(void* const* d_in, const int* in_sizes, int n_in,
                              void* d_out, int out_size, void* d_ws, size_t ws_size,
                              hipStream_t stream) {
    const float*    hs   = (const float*)d_in[0];
    const uint32_t* mask = (const uint32_t*)d_in[1];

    const int B  = 8;                       // per reference setup
    const int BS = in_sizes[1];             // B * S
    const int S  = BS / B;                  // 4096
    const int D  = in_sizes[0] / BS;        // 1024
    const int max_len = out_size / (B * D); // data-dependent but fixed per run
    const int stride  = (max_len + 3) & ~3; // idx row stride, 16B-aligned

    // workspace layout: counts[B] (first 256B for alignment), then idx[B*stride]
    int* counts = (int*)d_ws;
    int* idx    = (int*)((char*)d_ws + 256);

    compact_index_kernel<<<B, 64 * WAVES_A, 0, stream>>>(mask, S, stride, idx, counts);

    dim3 grid((max_len + 3) / 4, B);
    gather_pad_kernel<<<grid, 256, 0, stream>>>(
        hs, idx, counts, (float*)d_out, S, D, max_len, stride);
}

// Round 3
// 28.581 us; speedup vs baseline: 1.1836x; 1.0390x over previous
//
#include <hip/hip_runtime.h>
#include <hip/hip_bf16.h>
#include <stdint.h>

// ---------------------------------------------------------------------------
// Fully fused gather+pad. One kernel, one launch.
// Grid: (ceil(max_len/ROWS), B), 256 threads/block.
// Each block handles ROWS consecutive output rows of one batch row:
//   1. loads the whole 4096-entry boundary mask row (thread t covers 16
//      consecutive positions; vectorized uint4 loads; L2-resident),
//   2. shuffle+LDS exclusive prefix scan of per-thread popcounts,
//   3. the thread whose span contains the (j)-th set bit publishes its
//      position to LDS for each of the block's ROWS rows,
//   4. gathers ROWS x float4-per-thread with all loads issued before stores.
// Mask stored as 4-byte words (int32 0/1 or f32 1.0f) OR raw bytes,
// auto-detected from the first 64 words (256 B, in-bounds either way).
// ---------------------------------------------------------------------------
#define ROWS 8

__global__ void __launch_bounds__(256)
fused_gather_kernel(const float* __restrict__ hs,
                    const uint32_t* __restrict__ mask_words,
                    float* __restrict__ out,
                    int S, int D, int max_len) {
    const int b    = blockIdx.y;
    const int t    = threadIdx.x;        // 0..255
    const int wave = t >> 6;
    const int lane = t & 63;
    const int j0   = blockIdx.x * ROWS;

    // --- mask layout detection (word vs byte) -----------------------------
    uint32_t w0 = mask_words[lane];      // same 64 words per wave; cached
    bool weird = (w0 > 1u) && (w0 != 0x3F800000u);
    const bool bytemode = (__ballot(weird) != 0ULL);

    // --- load this thread's 16-position span of the mask row --------------
    // positions [t*16, t*16+16); S == 4096 == 256*16 per setup.
    const size_t row_base = (size_t)b * (size_t)S;
    uint32_t m16 = 0;
    if (bytemode) {
        const uint4* bp = (const uint4*)((const uint8_t*)mask_words + row_base) + t;
        uint4 a = *bp;
        uint32_t wrds[4] = {a.x, a.y, a.z, a.w};
        #pragma unroll
        for (int w = 0; w < 4; ++w)
            #pragma unroll
            for (int k = 0; k < 4; ++k)
                m16 |= (uint32_t)(((wrds[w] >> (8 * k)) & 0xffu) != 0u) << (w * 4 + k);
    } else {
        const uint4* wp = (const uint4*)(mask_words + row_base) + t * 4;
        #pragma unroll
        for (int q = 0; q < 4; ++q) {
            uint4 a = wp[q];
            m16 |= (uint32_t)(a.x != 0u) << (q * 4 + 0);
            m16 |= (uint32_t)(a.y != 0u) << (q * 4 + 1);
            m16 |= (uint32_t)(a.z != 0u) << (q * 4 + 2);
            m16 |= (uint32_t)(a.w != 0u) << (q * 4 + 3);
        }
    }
    const int lc = __popc(m16);

    // --- block-wide exclusive scan of per-thread counts -------------------
    int scan = lc;                        // wave-inclusive scan
    #pragma unroll
    for (int d = 1; d < 64; d <<= 1) {
        int n = __shfl_up(scan, d, 64);
        if (lane >= d) scan += n;
    }
    __shared__ int wtot[4];
    if (lane == 63) wtot[wave] = scan;
    __syncthreads();
    int wbase = 0;
    #pragma unroll
    for (int w = 0; w < 4; ++w) if (w < wave) wbase += wtot[w];
    const int cnt = wtot[0] + wtot[1] + wtot[2] + wtot[3];
    const int pre = wbase + scan - lc;   // exclusive prefix of this thread

    // --- locate source positions for this block's ROWS rows ---------------
    __shared__ int found[ROWS];
    #pragma unroll
    for (int r = 0; r < ROWS; ++r) {
        const int j = j0 + r;
        if (j < cnt && pre <= j && j < pre + lc) {
            int rem = j - pre;
            uint32_t m = m16;
            for (int k = 0; k < rem; ++k) m &= m - 1;   // drop lowest rem bits
            found[r] = t * 16 + __builtin_ctz(m);
        }
    }
    __syncthreads();

    // --- gather: issue all row loads, then all stores ----------------------
    float4 val[ROWS];
    #pragma unroll
    for (int r = 0; r < ROWS; ++r) {
        val[r] = make_float4(0.f, 0.f, 0.f, 0.f);
        const int j = j0 + r;
        if (j < cnt) {
            const int s = found[r];
            const float4* src =
                (const float4*)(hs + ((size_t)b * S + (size_t)s) * (size_t)D);
            val[r] = src[t];
        }
    }
    #pragma unroll
    for (int r = 0; r < ROWS; ++r) {
        const int j = j0 + r;
        if (j < max_len) {
            float4* dst =
                (float4*)(out + ((size_t)b * max_len + (size_t)j) * (size_t)D);
            dst[t] = val[r];
        }
    }
}

extern "C" void kernel_launch(void* const* d_in, const int* in_sizes, int n_in,
                              void* d_out, int out_size, void* d_ws, size_t ws_size,
                              hipStream_t stream) {
    const float*    hs   = (const float*)d_in[0];
    const uint32_t* mask = (const uint32_t*)d_in[1];

    const int B  = 8;                       // per reference setup
    const int BS = in_sizes[1];             // B * S
    const int S  = BS / B;                  // 4096
    const int D  = in_sizes[0] / BS;        // 1024
    const int max_len = out_size / (B * D); // data-dependent, fixed per run

    dim3 grid((max_len + ROWS - 1) / ROWS, B);
    fused_gather_kernel<<<grid, 256, 0, stream>>>(
        hs, mask, (float*)d_out, S, D, max_len);
}